// Round 10
// baseline (531.299 us; speedup 1.0000x reference)
//
#include <hip/hip_runtime.h>
#include <cstdint>
#include <cstddef>

typedef __attribute__((ext_vector_type(8))) __bf16 bf16x8;
typedef __attribute__((ext_vector_type(4))) float f32x4;

__device__ __forceinline__ float sigm(float v) { return 1.0f / (1.0f + expf(-v)); }

__device__ __forceinline__ float gelu_fast(float v) {
  float u = v * (1.0f + 0.044715f * v * v);
  float z = 1.5957691216057308f * u;
  return v / (1.0f + __expf(-z));
}

__device__ __forceinline__ void async16(__bf16* lds, const __bf16* g) {
  __builtin_amdgcn_global_load_lds(
      (const __attribute__((address_space(1))) void*)g,
      (__attribute__((address_space(3))) void*)lds, 16, 0, 0);
}

// ---------------- convert fp32 -> bf16, 8 elems/thread (x only) ----------------
__global__ __launch_bounds__(256) void k_convert(const float* __restrict__ src,
                                                 __bf16* __restrict__ dst, int n8) {
  int i = blockIdx.x * 256 + threadIdx.x;
  if (i >= n8) return;
  const f32x4* s4 = (const f32x4*)src;
  f32x4 a = s4[2 * i], b = s4[2 * i + 1];
  bf16x8 o;
#pragma unroll
  for (int e = 0; e < 4; ++e) { o[e] = (__bf16)a[e]; o[4 + e] = (__bf16)b[e]; }
  ((bf16x8*)dst)[i] = o;
}

// ---------------- merged prep: W converts + bcat + b2 ----------------
// blocks [0,288) Wh; [288,576) Ww; [576,864) Ws; [864,1152) projW->Pb;
// [1152,1161) bcat; [1161,1164) b2.
__global__ __launch_bounds__(256) void k_prep(
    const float* __restrict__ Wh, const float* __restrict__ Ww,
    const float* __restrict__ Ws, const float* __restrict__ projW,
    const float* __restrict__ bh, const float* __restrict__ bw,
    const float* __restrict__ bs, const float* __restrict__ mixallb,
    const float* __restrict__ projb, __bf16* __restrict__ Wcat,
    __bf16* __restrict__ Pb, float* __restrict__ bcat, float* __restrict__ b2) {
  const int bid = blockIdx.x, t = threadIdx.x;
  if (bid < 1152) {
    const int seg = bid / 288, loc = bid % 288;
    const float* src = seg == 0 ? Wh : (seg == 1 ? Ww : (seg == 2 ? Ws : projW));
    __bf16* dst = seg == 3 ? Pb : Wcat + (size_t)seg * 589824;
    const int i = loc * 256 + t;  // chunk of 8; 73728 per segment
    const f32x4* s4 = (const f32x4*)src;
    f32x4 a = s4[2 * i], b = s4[2 * i + 1];
    bf16x8 o;
#pragma unroll
    for (int e = 0; e < 4; ++e) { o[e] = (__bf16)a[e]; o[4 + e] = (__bf16)b[e]; }
    ((bf16x8*)dst)[i] = o;
  } else if (bid < 1161) {
    const int i = (bid - 1152) * 256 + t;
    if (i < 2304)
      bcat[i] = i < 768 ? bh[i] : (i < 1536 ? bw[i - 768] : bs[i - 1536]);
  } else {
    const int d = (bid - 1161) * 256 + t;
    float acc = projb[d];
    const float* row = projW + (size_t)d * 768;
#pragma unroll 4
    for (int c = 0; c < 768; c += 4) {
      f32x4 p4 = *(const f32x4*)(row + c);
      f32x4 b4 = *(const f32x4*)(mixallb + c);
      acc += p4[0] * b4[0] + p4[1] * b4[1] + p4[2] * b4[2] + p4[3] * b4[3];
    }
    b2[d] = acc;
  }
}

// transpose + convert: src (R x C) fp32 -> dst (C x R) bf16
__global__ __launch_bounds__(256) void k_transpose_cvt(const float* __restrict__ src,
                                                       __bf16* __restrict__ dst,
                                                       int R, int C) {
  __shared__ float t[32][33];
  const int c0 = blockIdx.x * 32, r0 = blockIdx.y * 32;
  const int tx = threadIdx.x, ty = threadIdx.y;  // 32 x 8
#pragma unroll
  for (int i = 0; i < 32; i += 8)
    if (r0 + ty + i < R && c0 + tx < C) t[ty + i][tx] = src[(size_t)(r0 + ty + i) * C + c0 + tx];
  __syncthreads();
#pragma unroll
  for (int i = 0; i < 32; i += 8)
    if (c0 + ty + i < C && r0 + tx < R)
      dst[(size_t)(c0 + ty + i) * R + r0 + tx] = (__bf16)t[tx][ty + i];
}

// ===== 256x128 GEMM body (BT layout), BK=32, 4 waves of 128x64, ring-3 LDS =====
// R8-proven schedule: 72KB ring-3, counted vmcnt(6), 2 blocks/CU, ~100 VGPR
// (no spill). R9 falsified ring-2/drain-vmcnt(0): GEMM1 150->254us. Keep counted.
// Swizzle (both-sides, rule #21): 16B chunk ch ^= (row>>1)&3 (R6-R9: conflicts=0).
template <int EPI>
__device__ __forceinline__ void gemm_body(
    __bf16* lds, const __bf16* __restrict__ A, const __bf16* __restrict__ B,
    const float* __restrict__ bias, __bf16* __restrict__ outB,
    float* __restrict__ outF, const float* __restrict__ xres,
    const float* __restrict__ gatew, int N, int K, int tm, int tn) {
  const int tid = threadIdx.x;
  const int lane = tid & 63, wid = tid >> 6;
  const int wr = wid >> 1, wc = wid & 1;

  const __bf16* Ag = A + (size_t)tm * 256 * K;
  const __bf16* Bg = B + (size_t)tn * 128 * K;

  auto stage = [&](int buf, int kt) {
    const int base = buf * 12288;
#pragma unroll
    for (int j = 0; j < 4; ++j) {
      const int lin = j * 256 + tid;
      const int row = lin >> 2, ch = lin & 3;
      async16(&lds[base + lin * 8],
              Ag + (size_t)row * K + kt * 32 + ((ch ^ ((row >> 1) & 3)) << 3));
    }
#pragma unroll
    for (int j = 0; j < 2; ++j) {
      const int lin = j * 256 + tid;
      const int row = lin >> 2, ch = lin & 3;
      async16(&lds[base + 8192 + lin * 8],
              Bg + (size_t)row * K + kt * 32 + ((ch ^ ((row >> 1) & 3)) << 3));
    }
  };

  f32x4 acc[8][4];
#pragma unroll
  for (int m = 0; m < 8; ++m)
#pragma unroll
    for (int n = 0; n < 4; ++n) acc[m][n] = f32x4{0.f, 0.f, 0.f, 0.f};

  const int kc = lane >> 4;
  const int rA = wr * 128 + (lane & 15);
  const int rB = wc * 64 + (lane & 15);
  const int chA = kc ^ ((rA >> 1) & 3);
  const int chB = kc ^ ((rB >> 1) & 3);
  const int NT = K >> 5;

  stage(0, 0);
  stage(1, 1);
  asm volatile("s_waitcnt vmcnt(6)" ::: "memory");
  __builtin_amdgcn_s_barrier();

  for (int t = 0; t < NT; ++t) {
    const int cb = (t % 3) * 12288;
    if (t + 2 < NT) stage((t + 2) % 3, t + 2);  // prefetch first
    bf16x8 af[8], bfv[4];
#pragma unroll
    for (int m = 0; m < 8; ++m)
      af[m] = *(const bf16x8*)&lds[cb + (rA + m * 16) * 32 + chA * 8];
#pragma unroll
    for (int n = 0; n < 4; ++n)
      bfv[n] = *(const bf16x8*)&lds[cb + 8192 + (rB + n * 16) * 32 + chB * 8];
    __builtin_amdgcn_s_setprio(1);
#pragma unroll
    for (int m = 0; m < 8; ++m)
#pragma unroll
      for (int n = 0; n < 4; ++n)
        acc[m][n] = __builtin_amdgcn_mfma_f32_16x16x32_bf16(af[m], bfv[n], acc[m][n], 0, 0, 0);
    __builtin_amdgcn_s_setprio(0);
    if (t + 2 < NT) { asm volatile("s_waitcnt vmcnt(6)" ::: "memory"); }
    else            { asm volatile("s_waitcnt vmcnt(0)" ::: "memory"); }
    __builtin_amdgcn_s_barrier();
  }

  // epilogue: C/D layout col=lane&15, row=(lane>>4)*4+reg  [m89]
  const int orow = (lane >> 4) * 4;
  const int ocol = lane & 15;
  float g0 = 0.f, g1 = 0.f;
  if constexpr (EPI == 2) { g0 = gatew[0]; g1 = gatew[1]; }
#pragma unroll
  for (int m = 0; m < 8; ++m) {
#pragma unroll
    for (int n = 0; n < 4; ++n) {
#pragma unroll
      for (int rr = 0; rr < 4; ++rr) {
        const int rg = tm * 256 + wr * 128 + m * 16 + orow + rr;
        const int cg = tn * 128 + wc * 64 + n * 16 + ocol;
        if constexpr (EPI == 0) {
          float v = acc[m][n][rr] + bias[cg];
          outB[(size_t)rg * N + cg] = (__bf16)gelu_fast(v);
        } else if constexpr (EPI == 2) {
          float v = acc[m][n][rr] + bias[cg];
          outF[(size_t)rg * N + cg] = g0 * v + g1 * xres[(size_t)rg * N + cg];
        } else {
          outB[(size_t)rg * N + cg] = (__bf16)acc[m][n][rr];
        }
      }
    }
  }
}

// fused: W2 = P.D (blocks [0,54)) + GEMM1 (blocks [54, 54+3528)); ring-3 body.
// 3582 blocks = exactly 7.0 rounds of 512 slots -> W2 hides in the rounds.
__global__ __launch_bounds__(256, 2) void k_gemm_fused(
    const __bf16* __restrict__ Pb, const __bf16* __restrict__ Dt,
    __bf16* __restrict__ W2, const __bf16* __restrict__ xb,
    const __bf16* __restrict__ Wcat, const float* __restrict__ bcat,
    __bf16* __restrict__ hws) {
  __shared__ __bf16 lds[36864];  // 72 KiB, ring-3
  if (blockIdx.x < 54) {
    const int tm = blockIdx.x / 18, tn = blockIdx.x % 18;
    gemm_body<3>(lds, Pb, Dt, nullptr, W2, nullptr, nullptr, nullptr,
                 2304, 768, tm, tn);
  } else {
    const int b = blockIdx.x - 54;  // 3528 blocks; 3528%8==0 -> simple XCD swizzle
    const int wgid = (b & 7) * 441 + (b >> 3);
    gemm_body<0>(lds, xb, Wcat, bcat, hws, nullptr, nullptr, nullptr,
                 2304, 768, wgid / 18, wgid % 18);
  }
}

// ===== GEMM2: 128x128 tile, 2 waves of 128x64, ring-3, vmcnt(8) (R8-proven) =====
__global__ __launch_bounds__(128, 2) void k_gemm2(
    const __bf16* __restrict__ A, const __bf16* __restrict__ B,
    const float* __restrict__ bias, float* __restrict__ outF,
    const float* __restrict__ xres, const float* __restrict__ gatew,
    int N, int K) {
  __shared__ __bf16 lds[24576];  // 3 x (A 128x32 + B 128x32) = 48 KiB
  const int tid = threadIdx.x;
  const int lane = tid & 63, wid = tid >> 6;
  const int wr = 0, wc = wid;

  const int nwg = gridDim.x;
  const int q = nwg >> 3, r = nwg & 7;
  const int xcd = blockIdx.x & 7, bidx = blockIdx.x >> 3;
  const int wgid = (xcd < r ? xcd * (q + 1) : r * (q + 1) + (xcd - r) * q) + bidx;
  const int nTn = N >> 7;
  const int tm = wgid / nTn, tn = wgid % nTn;

  const __bf16* Ag = A + (size_t)tm * 128 * K;
  const __bf16* Bg = B + (size_t)tn * 128 * K;

  auto stage = [&](int buf, int kt) {
    const int base = buf * 8192;
#pragma unroll
    for (int j = 0; j < 4; ++j) {
      const int lin = j * 128 + tid;
      const int row = lin >> 2, ch = lin & 3;
      async16(&lds[base + lin * 8],
              Ag + (size_t)row * K + kt * 32 + ((ch ^ ((row >> 1) & 3)) << 3));
    }
#pragma unroll
    for (int j = 0; j < 4; ++j) {
      const int lin = j * 128 + tid;
      const int row = lin >> 2, ch = lin & 3;
      async16(&lds[base + 4096 + lin * 8],
              Bg + (size_t)row * K + kt * 32 + ((ch ^ ((row >> 1) & 3)) << 3));
    }
  };

  f32x4 acc[8][4];
#pragma unroll
  for (int m = 0; m < 8; ++m)
#pragma unroll
    for (int n = 0; n < 4; ++n) acc[m][n] = f32x4{0.f, 0.f, 0.f, 0.f};

  const int kc = lane >> 4;
  const int rA = lane & 15;
  const int rB = wc * 64 + (lane & 15);
  const int chA = kc ^ ((rA >> 1) & 3);
  const int chB = kc ^ ((rB >> 1) & 3);
  const int NT = K >> 5;

  stage(0, 0);
  stage(1, 1);
  asm volatile("s_waitcnt vmcnt(8)" ::: "memory");
  __builtin_amdgcn_s_barrier();

  for (int t = 0; t < NT; ++t) {
    const int cb = (t % 3) * 8192;
    if (t + 2 < NT) stage((t + 2) % 3, t + 2);
    bf16x8 af[8], bfv[4];
#pragma unroll
    for (int m = 0; m < 8; ++m)
      af[m] = *(const bf16x8*)&lds[cb + (rA + m * 16) * 32 + chA * 8];
#pragma unroll
    for (int n = 0; n < 4; ++n)
      bfv[n] = *(const bf16x8*)&lds[cb + 4096 + (rB + n * 16) * 32 + chB * 8];
    __builtin_amdgcn_s_setprio(1);
#pragma unroll
    for (int m = 0; m < 8; ++m)
#pragma unroll
      for (int n = 0; n < 4; ++n)
        acc[m][n] = __builtin_amdgcn_mfma_f32_16x16x32_bf16(af[m], bfv[n], acc[m][n], 0, 0, 0);
    __builtin_amdgcn_s_setprio(0);
    if (t + 2 < NT) { asm volatile("s_waitcnt vmcnt(8)" ::: "memory"); }
    else            { asm volatile("s_waitcnt vmcnt(0)" ::: "memory"); }
    __builtin_amdgcn_s_barrier();
  }

  const int orow = (lane >> 4) * 4;
  const int ocol = lane & 15;
  const float g0 = gatew[0], g1 = gatew[1];
#pragma unroll
  for (int m = 0; m < 8; ++m) {
#pragma unroll
    for (int n = 0; n < 4; ++n) {
#pragma unroll
      for (int rr = 0; rr < 4; ++rr) {
        const int rg = tm * 128 + m * 16 + orow + rr;
        const int cg = tn * 128 + wc * 64 + n * 16 + ocol;
        float v = acc[m][n][rr] + bias[cg];
        outF[(size_t)rg * N + cg] = g0 * v + g1 * xres[(size_t)rg * N + cg];
      }
    }
  }
}

// ---------------- pooling: h2v (B,7), w2v (B,7), s1v (B,768) ----------------
__global__ __launch_bounds__(256) void k_pool(const __bf16* __restrict__ hws,
                                              float* __restrict__ h2v,
                                              float* __restrict__ w2v,
                                              float* __restrict__ s1v) {
  const int b = blockIdx.x, t = threadIdx.x;
  const int lane = t & 63, wave = t >> 6;
  const size_t base = (size_t)b * 49 * 2304;
  float hloc[7], wloc[7];
#pragma unroll
  for (int i = 0; i < 7; ++i) { hloc[i] = 0.f; wloc[i] = 0.f; }
  float sacc[8], sacc2[8];
#pragma unroll
  for (int e = 0; e < 8; ++e) { sacc[e] = 0.f; sacc2[e] = 0.f; }

  const bool isH = t < 96, isW = (t >= 96 && t < 192);
  const int off1 = isH ? t * 8 : (isW ? 768 + (t - 96) * 8 : 1536 + (t - 192) * 8);
  const int off2 = 1536 + (64 + t) * 8;

#pragma unroll
  for (int p = 0; p < 49; ++p) {
    const int hi = p / 7, wi = p % 7;
    const __bf16* row = hws + base + (size_t)p * 2304;
    bf16x8 v = *(const bf16x8*)(row + off1);
    float s8 = 0.f;
#pragma unroll
    for (int e = 0; e < 8; ++e) s8 += (float)v[e];
    if (isH) hloc[hi] += s8;
    else if (isW) wloc[wi] += s8;
    else {
#pragma unroll
      for (int e = 0; e < 8; ++e) sacc[e] += (float)v[e];
    }
    if (t < 32) {
      bf16x8 v2 = *(const bf16x8*)(row + off2);
#pragma unroll
      for (int e = 0; e < 8; ++e) sacc2[e] += (float)v2[e];
    }
  }

  if (t >= 192) {
#pragma unroll
    for (int e = 0; e < 8; ++e)
      s1v[b * 768 + (t - 192) * 8 + e] = sacc[e] * (1.f / 49.f);
  }
  if (t < 32) {
#pragma unroll
    for (int e = 0; e < 8; ++e)
      s1v[b * 768 + 512 + t * 8 + e] = sacc2[e] * (1.f / 49.f);
  }

  __shared__ float red[4][14];
#pragma unroll
  for (int i = 0; i < 7; ++i) {
    float hv = hloc[i], wv = wloc[i];
#pragma unroll
    for (int s = 32; s; s >>= 1) { hv += __shfl_xor(hv, s); wv += __shfl_xor(wv, s); }
    if (lane == 0) { red[wave][i] = hv; red[wave][7 + i] = wv; }
  }
  __syncthreads();
  if (t < 7) {
    h2v[b * 7 + t] = (red[0][t] + red[1][t] + red[2][t] + red[3][t]) * (1.f / 5376.f);
  } else if (t >= 16 && t < 23) {
    const int i = t - 16;
    w2v[b * 7 + i] =
        (red[0][7 + i] + red[1][7 + i] + red[2][7 + i] + red[3][7 + i]) * (1.f / 5376.f);
  }
}

// ---------------- gates: g_h (B,7), g_hw (B,7), g_c (B,768) ----------------
__global__ __launch_bounds__(256) void k_gates(
    const float* __restrict__ h2v, const float* __restrict__ w2v,
    const float* __restrict__ s1v, const float* __restrict__ convH_w,
    const float* __restrict__ convH_b, const float* __restrict__ convH2_k,
    const float* __restrict__ convH2_b, const float* __restrict__ mixhw_k,
    const float* __restrict__ mixhw_b, const float* __restrict__ mixhw2_k,
    const float* __restrict__ mixhw2_b, const float* __restrict__ mixhws_k,
    const float* __restrict__ mixhws_b, const float* __restrict__ mixhws2_k,
    const float* __restrict__ mixhws2_b, const float* __restrict__ linHW,
    const float* __restrict__ linHb, const float* __restrict__ linWW,
    const float* __restrict__ linWb, float* __restrict__ g_h,
    float* __restrict__ g_hw, float* __restrict__ g_c) {
  const int b = blockIdx.x, t = threadIdx.x;
  __shared__ float hv[7], wv[7];
  __shared__ float tc[770];
  if (t < 7) { hv[t] = h2v[b * 7 + t]; wv[t] = w2v[b * 7 + t]; }
  if (t == 7) { tc[0] = 0.f; tc[769] = 0.f; }
  __syncthreads();

  if (t < 7) {
    const float cw = convH_w[0], cbv = convH_b[0];
    const float k0 = convH2_k[0], k1 = convH2_k[1], k2 = convH2_k[2], b2 = convH2_b[0];
    const float um = t > 0 ? sigm(hv[t - 1] * cw + cbv) : 0.f;
    const float u0 = sigm(hv[t] * cw + cbv);
    const float up = t < 6 ? sigm(hv[t + 1] * cw + cbv) : 0.f;
    g_h[b * 7 + t] = sigm(k0 * um + k1 * u0 + k2 * up + b2);

    const float a0 = mixhw_k[0], a1 = mixhw_k[1], ab = mixhw_b[0];
    const float q0 = mixhw2_k[0], q1 = mixhw2_k[1], q2 = mixhw2_k[2], qb = mixhw2_b[0];
    const float vm = t > 0 ? sigm(a0 * hv[t - 1] + a1 * wv[t - 1] + ab) : 0.f;
    const float v0 = sigm(a0 * hv[t] + a1 * wv[t] + ab);
    const float vp = t < 6 ? sigm(a0 * hv[t + 1] + a1 * wv[t + 1] + ab) : 0.f;
    g_hw[b * 7 + t] = sigm(q0 * vm + q1 * v0 + q2 * vp + qb);
  }

  const float m0 = mixhws_k[0], m1 = mixhws_k[1], m2 = mixhws_k[2], mb = mixhws_b[0];
#pragma unroll
  for (int j = 0; j < 3; ++j) {
    const int c = t + j * 256;
    float h2l = linHb[c], w2l = linWb[c];
#pragma unroll
    for (int i = 0; i < 7; ++i) {
      h2l += hv[i] * linHW[c * 7 + i];
      w2l += wv[i] * linWW[c * 7 + i];
    }
    tc[1 + c] = sigm(m0 * h2l + m1 * w2l + m2 * s1v[b * 768 + c] + mb);
  }
  __syncthreads();
  const float r0 = mixhws2_k[0], r1 = mixhws2_k[1], r2 = mixhws2_k[2], rb2 = mixhws2_b[0];
#pragma unroll
  for (int j = 0; j < 3; ++j) {
    const int c = t + j * 256;
    g_c[b * 768 + c] = sigm(r0 * tc[c] + r1 * tc[c + 1] + r2 * tc[c + 2] + rb2);
  }
}

// ---------------- apply gates in place on hws ----------------
__global__ __launch_bounds__(256) void k_gapply(__bf16* __restrict__ hws,
                                                const float* __restrict__ g_h,
                                                const float* __restrict__ g_hw,
                                                const float* __restrict__ g_c) {
  const int idx = blockIdx.x * 256 + threadIdx.x;  // chunk of 8 bf16
  const int k8 = idx % 288;
  const int p = idx / 288;
  const int b = p / 49, pp = p % 49;
  bf16x8* ptr = (bf16x8*)hws + idx;
  bf16x8 v = *ptr;
  if (k8 < 96) {
    const float g = g_h[b * 7 + pp / 7];
#pragma unroll
    for (int e = 0; e < 8; ++e) v[e] = (__bf16)((float)v[e] * g);
  } else if (k8 < 192) {
    const float g = g_hw[b * 7 + pp % 7];
#pragma unroll
    for (int e = 0; e < 8; ++e) v[e] = (__bf16)((float)v[e] * g);
  } else {
    const float* gcp = g_c + b * 768 + (k8 - 192) * 8;
#pragma unroll
    for (int e = 0; e < 8; ++e) v[e] = (__bf16)((float)v[e] * gcp[e]);
  }
  *ptr = v;
}

// ---------------- launch ----------------
extern "C" void kernel_launch(void* const* d_in, const int* in_sizes, int n_in,
                              void* d_out, int out_size, void* d_ws, size_t ws_size,
                              hipStream_t stream) {
  const float* x        = (const float*)d_in[0];
  const float* Wh       = (const float*)d_in[1];
  const float* bh       = (const float*)d_in[2];
  const float* Ww       = (const float*)d_in[3];
  const float* bw       = (const float*)d_in[4];
  const float* Ws       = (const float*)d_in[5];
  const float* bs       = (const float*)d_in[6];
  const float* convH_w  = (const float*)d_in[7];
  const float* convH_b  = (const float*)d_in[8];
  const float* convH2_k = (const float*)d_in[9];
  const float* convH2_b = (const float*)d_in[10];
  const float* mixhw_k  = (const float*)d_in[11];
  const float* mixhw_b  = (const float*)d_in[12];
  const float* mixhw2_k = (const float*)d_in[13];
  const float* mixhw2_b = (const float*)d_in[14];
  const float* mixhws_k = (const float*)d_in[15];
  const float* mixhws_b = (const float*)d_in[16];
  const float* mixhws2_k= (const float*)d_in[17];
  const float* mixhws2_b= (const float*)d_in[18];
  const float* linHW    = (const float*)d_in[19];
  const float* linHb    = (const float*)d_in[20];
  const float* linWW    = (const float*)d_in[21];
  const float* linWb    = (const float*)d_in[22];
  const float* mixallW  = (const float*)d_in[23];
  const float* mixallb  = (const float*)d_in[24];
  const float* projW    = (const float*)d_in[25];
  const float* projb    = (const float*)d_in[26];
  const float* gatew    = (const float*)d_in[27];
  float* out = (float*)d_out;
  (void)in_sizes; (void)n_in; (void)out_size; (void)ws_size;

  const int M = 25088;  // 512*7*7
  char* ws = (char*)d_ws;
  size_t off = 0;
  auto carve = [&](size_t bytes) -> void* {
    void* p = ws + off;
    off += (bytes + 255) & ~(size_t)255;
    return p;
  };
  __bf16* xb     = (__bf16*)carve((size_t)M * 768 * 2);
  __bf16* Wcat   = (__bf16*)carve((size_t)2304 * 768 * 2);
  __bf16* Pb     = (__bf16*)carve((size_t)768 * 768 * 2);
  __bf16* Dt     = (__bf16*)carve((size_t)2304 * 768 * 2);
  __bf16* W2     = (__bf16*)carve((size_t)768 * 2304 * 2);
  float*  bcat   = (float*)carve(2304 * 4);
  float*  b2     = (float*)carve(768 * 4);
  __bf16* hws    = (__bf16*)carve((size_t)M * 2304 * 2);
  float*  h2v    = (float*)carve(512 * 7 * 4);
  float*  w2v    = (float*)carve(512 * 7 * 4);
  float*  s1v    = (float*)carve(512 * 768 * 4);
  float*  gh     = (float*)carve(512 * 7 * 4);
  float*  ghw    = (float*)carve(512 * 7 * 4);
  float*  gc     = (float*)carve(512 * 768 * 4);

  k_convert<<<9408, 256, 0, stream>>>(x, xb, (M * 768) / 8);
  k_prep<<<1164, 256, 0, stream>>>(Wh, Ww, Ws, projW, bh, bw, bs, mixallb, projb,
                                   Wcat, Pb, bcat, b2);
  k_transpose_cvt<<<dim3(72, 24), dim3(32, 8), 0, stream>>>(mixallW, Dt, 768, 2304);

  // fused: W2 = P.D (54 blocks) + [h|w|s] = gelu(x@[Wh|Ww|Ws]^T + bcat) (3528)
  k_gemm_fused<<<54 + 3528, 256, 0, stream>>>(Pb, Dt, W2, xb, Wcat, bcat, hws);
  k_pool<<<512, 256, 0, stream>>>(hws, h2v, w2v, s1v);
  k_gates<<<512, 256, 0, stream>>>(h2v, w2v, s1v, convH_w, convH_b, convH2_k,
                                   convH2_b, mixhw_k, mixhw_b, mixhw2_k, mixhw2_b,
                                   mixhws_k, mixhws_b, mixhws2_k, mixhws2_b,
                                   linHW, linHb, linWW, linWb, gh, ghw, gc);
  k_gapply<<<28224, 256, 0, stream>>>(hws, gh, ghw, gc);
  // out = g0*(cat @ W2^T + b2) + g1*x  (M x 768, K=2304) — 128-tile, 2-wave, ring-3
  k_gemm2<<<196 * 6, 128, 0, stream>>>(hws, W2, b2, out, x, gatew, 768, 2304);
}

// Round 11
// 375.091 us; speedup vs baseline: 1.4165x; 1.4165x over previous
//
#include <hip/hip_runtime.h>
#include <cstdint>
#include <cstddef>

typedef __attribute__((ext_vector_type(8))) __bf16 bf16x8;
typedef __attribute__((ext_vector_type(4))) float f32x4;

__device__ __forceinline__ float sigm(float v) { return 1.0f / (1.0f + expf(-v)); }

__device__ __forceinline__ float gelu_fast(float v) {
  float u = v * (1.0f + 0.044715f * v * v);
  float z = 1.5957691216057308f * u;
  return v / (1.0f + __expf(-z));
}

__device__ __forceinline__ void async16(__bf16* lds, const __bf16* g) {
  __builtin_amdgcn_global_load_lds(
      (const __attribute__((address_space(1))) void*)g,
      (__attribute__((address_space(3))) void*)lds, 16, 0, 0);
}

// ---------------- convert fp32 -> bf16, 8 elems/thread (x only) ----------------
__global__ __launch_bounds__(256) void k_convert(const float* __restrict__ src,
                                                 __bf16* __restrict__ dst, int n8) {
  int i = blockIdx.x * 256 + threadIdx.x;
  if (i >= n8) return;
  const f32x4* s4 = (const f32x4*)src;
  f32x4 a = s4[2 * i], b = s4[2 * i + 1];
  bf16x8 o;
#pragma unroll
  for (int e = 0; e < 4; ++e) { o[e] = (__bf16)a[e]; o[4 + e] = (__bf16)b[e]; }
  ((bf16x8*)dst)[i] = o;
}

// ---------------- merged prep: W converts + bcat + b2 ----------------
__global__ __launch_bounds__(256) void k_prep(
    const float* __restrict__ Wh, const float* __restrict__ Ww,
    const float* __restrict__ Ws, const float* __restrict__ projW,
    const float* __restrict__ bh, const float* __restrict__ bw,
    const float* __restrict__ bs, const float* __restrict__ mixallb,
    const float* __restrict__ projb, __bf16* __restrict__ Wcat,
    __bf16* __restrict__ Pb, float* __restrict__ bcat, float* __restrict__ b2) {
  const int bid = blockIdx.x, t = threadIdx.x;
  if (bid < 1152) {
    const int seg = bid / 288, loc = bid % 288;
    const float* src = seg == 0 ? Wh : (seg == 1 ? Ww : (seg == 2 ? Ws : projW));
    __bf16* dst = seg == 3 ? Pb : Wcat + (size_t)seg * 589824;
    const int i = loc * 256 + t;
    const f32x4* s4 = (const f32x4*)src;
    f32x4 a = s4[2 * i], b = s4[2 * i + 1];
    bf16x8 o;
#pragma unroll
    for (int e = 0; e < 4; ++e) { o[e] = (__bf16)a[e]; o[4 + e] = (__bf16)b[e]; }
    ((bf16x8*)dst)[i] = o;
  } else if (bid < 1161) {
    const int i = (bid - 1152) * 256 + t;
    if (i < 2304)
      bcat[i] = i < 768 ? bh[i] : (i < 1536 ? bw[i - 768] : bs[i - 1536]);
  } else {
    const int d = (bid - 1161) * 256 + t;
    float acc = projb[d];
    const float* row = projW + (size_t)d * 768;
#pragma unroll 4
    for (int c = 0; c < 768; c += 4) {
      f32x4 p4 = *(const f32x4*)(row + c);
      f32x4 b4 = *(const f32x4*)(mixallb + c);
      acc += p4[0] * b4[0] + p4[1] * b4[1] + p4[2] * b4[2] + p4[3] * b4[3];
    }
    b2[d] = acc;
  }
}

// transpose + convert: src (R x C) fp32 -> dst (C x R) bf16
__global__ __launch_bounds__(256) void k_transpose_cvt(const float* __restrict__ src,
                                                       __bf16* __restrict__ dst,
                                                       int R, int C) {
  __shared__ float t[32][33];
  const int c0 = blockIdx.x * 32, r0 = blockIdx.y * 32;
  const int tx = threadIdx.x, ty = threadIdx.y;  // 32 x 8
#pragma unroll
  for (int i = 0; i < 32; i += 8)
    if (r0 + ty + i < R && c0 + tx < C) t[ty + i][tx] = src[(size_t)(r0 + ty + i) * C + c0 + tx];
  __syncthreads();
#pragma unroll
  for (int i = 0; i < 32; i += 8)
    if (c0 + ty + i < C && r0 + tx < R)
      dst[(size_t)(c0 + ty + i) * R + r0 + tx] = (__bf16)t[tx][ty + i];
}

// ===== 256x128 GEMM body (BT layout), BK=32, 4 waves of 128x64, ring-3 LDS =====
// R8-proven: 72KB ring-3, counted vmcnt(6), 2 blocks/CU, ~100-104 VGPR (no spill).
// Per-block rate ~690-714 TF at full tail amortization (R10 normalized).
// Swizzle (both-sides, rule #21): 16B chunk ch ^= (row>>1)&3 (R6-R10: conflicts=0).
template <int EPI>
__device__ __forceinline__ void gemm_body(
    __bf16* lds, const __bf16* __restrict__ A, const __bf16* __restrict__ B,
    const float* __restrict__ bias, __bf16* __restrict__ outB,
    float* __restrict__ outF, const float* __restrict__ xres,
    const float* __restrict__ gatew, int N, int K, int tm, int tn) {
  const int tid = threadIdx.x;
  const int lane = tid & 63, wid = tid >> 6;
  const int wr = wid >> 1, wc = wid & 1;

  const __bf16* Ag = A + (size_t)tm * 256 * K;
  const __bf16* Bg = B + (size_t)tn * 128 * K;

  auto stage = [&](int buf, int kt) {
    const int base = buf * 12288;
#pragma unroll
    for (int j = 0; j < 4; ++j) {
      const int lin = j * 256 + tid;
      const int row = lin >> 2, ch = lin & 3;
      async16(&lds[base + lin * 8],
              Ag + (size_t)row * K + kt * 32 + ((ch ^ ((row >> 1) & 3)) << 3));
    }
#pragma unroll
    for (int j = 0; j < 2; ++j) {
      const int lin = j * 256 + tid;
      const int row = lin >> 2, ch = lin & 3;
      async16(&lds[base + 8192 + lin * 8],
              Bg + (size_t)row * K + kt * 32 + ((ch ^ ((row >> 1) & 3)) << 3));
    }
  };

  f32x4 acc[8][4];
#pragma unroll
  for (int m = 0; m < 8; ++m)
#pragma unroll
    for (int n = 0; n < 4; ++n) acc[m][n] = f32x4{0.f, 0.f, 0.f, 0.f};

  const int kc = lane >> 4;
  const int rA = wr * 128 + (lane & 15);
  const int rB = wc * 64 + (lane & 15);
  const int chA = kc ^ ((rA >> 1) & 3);
  const int chB = kc ^ ((rB >> 1) & 3);
  const int NT = K >> 5;

  stage(0, 0);
  stage(1, 1);
  asm volatile("s_waitcnt vmcnt(6)" ::: "memory");
  __builtin_amdgcn_s_barrier();

  for (int t = 0; t < NT; ++t) {
    const int cb = (t % 3) * 12288;
    if (t + 2 < NT) stage((t + 2) % 3, t + 2);  // prefetch first
    bf16x8 af[8], bfv[4];
#pragma unroll
    for (int m = 0; m < 8; ++m)
      af[m] = *(const bf16x8*)&lds[cb + (rA + m * 16) * 32 + chA * 8];
#pragma unroll
    for (int n = 0; n < 4; ++n)
      bfv[n] = *(const bf16x8*)&lds[cb + 8192 + (rB + n * 16) * 32 + chB * 8];
    __builtin_amdgcn_s_setprio(1);
#pragma unroll
    for (int m = 0; m < 8; ++m)
#pragma unroll
      for (int n = 0; n < 4; ++n)
        acc[m][n] = __builtin_amdgcn_mfma_f32_16x16x32_bf16(af[m], bfv[n], acc[m][n], 0, 0, 0);
    __builtin_amdgcn_s_setprio(0);
    if (t + 2 < NT) { asm volatile("s_waitcnt vmcnt(6)" ::: "memory"); }
    else            { asm volatile("s_waitcnt vmcnt(0)" ::: "memory"); }
    __builtin_amdgcn_s_barrier();
  }

  // epilogue: C/D layout col=lane&15, row=(lane>>4)*4+reg  [m89]
  const int orow = (lane >> 4) * 4;
  const int ocol = lane & 15;
  float g0 = 0.f, g1 = 0.f;
  if constexpr (EPI == 2) { g0 = gatew[0]; g1 = gatew[1]; }
#pragma unroll
  for (int m = 0; m < 8; ++m) {
#pragma unroll
    for (int n = 0; n < 4; ++n) {
#pragma unroll
      for (int rr = 0; rr < 4; ++rr) {
        const int rg = tm * 256 + wr * 128 + m * 16 + orow + rr;
        const int cg = tn * 128 + wc * 64 + n * 16 + ocol;
        if constexpr (EPI == 0) {
          float v = acc[m][n][rr] + bias[cg];
          outB[(size_t)rg * N + cg] = (__bf16)gelu_fast(v);
        } else if constexpr (EPI == 2) {
          float v = acc[m][n][rr] + bias[cg];
          outF[(size_t)rg * N + cg] = g0 * v + g1 * xres[(size_t)rg * N + cg];
        } else {
          outB[(size_t)rg * N + cg] = (__bf16)acc[m][n][rr];
        }
      }
    }
  }
}

__device__ __forceinline__ int swz_bij(int b, int nwg) {
  const int q = nwg >> 3, r = nwg & 7;
  const int xcd = b & 7, idx = b >> 3;
  return (xcd < r ? xcd * (q + 1) : r * (q + 1) + (xcd - r) * q) + idx;
}

// fused: W2 = P.D (blocks [0,54)) + GEMM1 (blocks [54, 54+1764)).  [R9/R10 had
// 3528 here -- 2x over-launch bug; GEMM1 tiles = 98*18 = 1764]
__global__ __launch_bounds__(256, 2) void k_gemm_fused(
    const __bf16* __restrict__ Pb, const __bf16* __restrict__ Dt,
    __bf16* __restrict__ W2, const __bf16* __restrict__ xb,
    const __bf16* __restrict__ Wcat, const float* __restrict__ bcat,
    __bf16* __restrict__ hws) {
  __shared__ __bf16 lds[36864];  // 72 KiB, ring-3
  if (blockIdx.x < 54) {
    const int tm = blockIdx.x / 18, tn = blockIdx.x % 18;
    gemm_body<3>(lds, Pb, Dt, nullptr, W2, nullptr, nullptr, nullptr,
                 2304, 768, tm, tn);
  } else {
    const int wgid = swz_bij(blockIdx.x - 54, 1764);
    gemm_body<0>(lds, xb, Wcat, bcat, hws, nullptr, nullptr, nullptr,
                 2304, 768, wgid / 18, wgid % 18);
  }
}

// GEMM2: 588 blocks (98 x 6), same 4-wave ring-3 body (R5-measured 156us)
__global__ __launch_bounds__(256, 2) void k_gemm2(
    const __bf16* __restrict__ hws, const __bf16* __restrict__ W2,
    const float* __restrict__ b2, float* __restrict__ out,
    const float* __restrict__ x, const float* __restrict__ gatew) {
  __shared__ __bf16 lds[36864];
  const int wgid = swz_bij(blockIdx.x, 588);
  gemm_body<2>(lds, hws, W2, b2, nullptr, out, x, gatew,
               768, 2304, wgid / 6, wgid % 6);
}

// ---------------- fused pool + gates + gate-apply (one block per batch) -------
// Gates depend only on per-batch pooled stats; block b owns batch b's 49x2304
// slab. Pool stats stay in LDS; gapply re-read hits L2/L3 (225 KB slab, hws
// fully L3-resident). Saves one full HBM read of hws (~115 MB) + 2 launches.
__global__ __launch_bounds__(256) void k_poolgate(
    __bf16* __restrict__ hws, const float* __restrict__ convH_w,
    const float* __restrict__ convH_b, const float* __restrict__ convH2_k,
    const float* __restrict__ convH2_b, const float* __restrict__ mixhw_k,
    const float* __restrict__ mixhw_b, const float* __restrict__ mixhw2_k,
    const float* __restrict__ mixhw2_b, const float* __restrict__ mixhws_k,
    const float* __restrict__ mixhws_b, const float* __restrict__ mixhws2_k,
    const float* __restrict__ mixhws2_b, const float* __restrict__ linHW,
    const float* __restrict__ linHb, const float* __restrict__ linWW,
    const float* __restrict__ linWb) {
  const int b = blockIdx.x, t = threadIdx.x;
  const int lane = t & 63, wave = t >> 6;
  const size_t base = (size_t)b * 49 * 2304;

  __shared__ float red[4][14];
  __shared__ float s1v[768];
  __shared__ float hv[7], wv[7];
  __shared__ float ghl[7], ghwl[7];
  __shared__ float tc[770];
  __shared__ float gcl[768];

  // ---- phase 1: pool ----
  float hloc[7], wloc[7];
#pragma unroll
  for (int i = 0; i < 7; ++i) { hloc[i] = 0.f; wloc[i] = 0.f; }
  float sacc[8], sacc2[8];
#pragma unroll
  for (int e = 0; e < 8; ++e) { sacc[e] = 0.f; sacc2[e] = 0.f; }

  const bool isH = t < 96, isW = (t >= 96 && t < 192);
  const int off1 = isH ? t * 8 : (isW ? 768 + (t - 96) * 8 : 1536 + (t - 192) * 8);
  const int off2 = 1536 + (64 + t) * 8;

#pragma unroll
  for (int p = 0; p < 49; ++p) {
    const int hi = p / 7, wi = p % 7;
    const __bf16* row = hws + base + (size_t)p * 2304;
    bf16x8 v = *(const bf16x8*)(row + off1);
    float s8 = 0.f;
#pragma unroll
    for (int e = 0; e < 8; ++e) s8 += (float)v[e];
    if (isH) hloc[hi] += s8;
    else if (isW) wloc[wi] += s8;
    else {
#pragma unroll
      for (int e = 0; e < 8; ++e) sacc[e] += (float)v[e];
    }
    if (t < 32) {
      bf16x8 v2 = *(const bf16x8*)(row + off2);
#pragma unroll
      for (int e = 0; e < 8; ++e) sacc2[e] += (float)v2[e];
    }
  }

  if (t >= 192) {
#pragma unroll
    for (int e = 0; e < 8; ++e) s1v[(t - 192) * 8 + e] = sacc[e] * (1.f / 49.f);
  }
  if (t < 32) {
#pragma unroll
    for (int e = 0; e < 8; ++e) s1v[512 + t * 8 + e] = sacc2[e] * (1.f / 49.f);
  }

#pragma unroll
  for (int i = 0; i < 7; ++i) {
    float hvx = hloc[i], wvx = wloc[i];
#pragma unroll
    for (int s = 32; s; s >>= 1) { hvx += __shfl_xor(hvx, s); wvx += __shfl_xor(wvx, s); }
    if (lane == 0) { red[wave][i] = hvx; red[wave][7 + i] = wvx; }
  }
  if (t == 8) { tc[0] = 0.f; tc[769] = 0.f; }
  __syncthreads();

  if (t < 7) {
    hv[t] = (red[0][t] + red[1][t] + red[2][t] + red[3][t]) * (1.f / 5376.f);
  } else if (t >= 16 && t < 23) {
    const int i = t - 16;
    wv[i] = (red[0][7 + i] + red[1][7 + i] + red[2][7 + i] + red[3][7 + i]) * (1.f / 5376.f);
  }
  __syncthreads();

  // ---- phase 2: gates ----
  if (t < 7) {
    const float cw = convH_w[0], cbv = convH_b[0];
    const float k0 = convH2_k[0], k1 = convH2_k[1], k2 = convH2_k[2], b2v = convH2_b[0];
    const float um = t > 0 ? sigm(hv[t - 1] * cw + cbv) : 0.f;
    const float u0 = sigm(hv[t] * cw + cbv);
    const float up = t < 6 ? sigm(hv[t + 1] * cw + cbv) : 0.f;
    ghl[t] = sigm(k0 * um + k1 * u0 + k2 * up + b2v);

    const float a0 = mixhw_k[0], a1 = mixhw_k[1], ab = mixhw_b[0];
    const float q0 = mixhw2_k[0], q1 = mixhw2_k[1], q2 = mixhw2_k[2], qb = mixhw2_b[0];
    const float vm = t > 0 ? sigm(a0 * hv[t - 1] + a1 * wv[t - 1] + ab) : 0.f;
    const float v0 = sigm(a0 * hv[t] + a1 * wv[t] + ab);
    const float vp = t < 6 ? sigm(a0 * hv[t + 1] + a1 * wv[t + 1] + ab) : 0.f;
    ghwl[t] = sigm(q0 * vm + q1 * v0 + q2 * vp + qb);
  }

  const float m0 = mixhws_k[0], m1 = mixhws_k[1], m2 = mixhws_k[2], mb = mixhws_b[0];
#pragma unroll
  for (int j = 0; j < 3; ++j) {
    const int c = t + j * 256;
    float h2l = linHb[c], w2l = linWb[c];
#pragma unroll
    for (int i = 0; i < 7; ++i) {
      h2l += hv[i] * linHW[c * 7 + i];
      w2l += wv[i] * linWW[c * 7 + i];
    }
    tc[1 + c] = sigm(m0 * h2l + m1 * w2l + m2 * s1v[c] + mb);
  }
  __syncthreads();
  const float r0 = mixhws2_k[0], r1 = mixhws2_k[1], r2 = mixhws2_k[2], rb2 = mixhws2_b[0];
#pragma unroll
  for (int j = 0; j < 3; ++j) {
    const int c = t + j * 256;
    gcl[c] = sigm(r0 * tc[c] + r1 * tc[c + 1] + r2 * tc[c + 2] + rb2);
  }
  __syncthreads();

  // ---- phase 3: apply gates in place (re-read hits L2/L3) ----
  bf16x8* slab = (bf16x8*)(hws + base);  // 49*288 chunks of 8
  for (int i = t; i < 49 * 288; i += 256) {
    const int k8 = i % 288, p = i / 288;
    bf16x8 v = slab[i];
    if (k8 < 96) {
      const float g = ghl[p / 7];
#pragma unroll
      for (int e = 0; e < 8; ++e) v[e] = (__bf16)((float)v[e] * g);
    } else if (k8 < 192) {
      const float g = ghwl[p % 7];
#pragma unroll
      for (int e = 0; e < 8; ++e) v[e] = (__bf16)((float)v[e] * g);
    } else {
      const float* gcp = gcl + (k8 - 192) * 8;
#pragma unroll
      for (int e = 0; e < 8; ++e) v[e] = (__bf16)((float)v[e] * gcp[e]);
    }
    slab[i] = v;
  }
}

// ---------------- launch ----------------
extern "C" void kernel_launch(void* const* d_in, const int* in_sizes, int n_in,
                              void* d_out, int out_size, void* d_ws, size_t ws_size,
                              hipStream_t stream) {
  const float* x        = (const float*)d_in[0];
  const float* Wh       = (const float*)d_in[1];
  const float* bh       = (const float*)d_in[2];
  const float* Ww       = (const float*)d_in[3];
  const float* bw       = (const float*)d_in[4];
  const float* Ws       = (const float*)d_in[5];
  const float* bs       = (const float*)d_in[6];
  const float* convH_w  = (const float*)d_in[7];
  const float* convH_b  = (const float*)d_in[8];
  const float* convH2_k = (const float*)d_in[9];
  const float* convH2_b = (const float*)d_in[10];
  const float* mixhw_k  = (const float*)d_in[11];
  const float* mixhw_b  = (const float*)d_in[12];
  const float* mixhw2_k = (const float*)d_in[13];
  const float* mixhw2_b = (const float*)d_in[14];
  const float* mixhws_k = (const float*)d_in[15];
  const float* mixhws_b = (const float*)d_in[16];
  const float* mixhws2_k= (const float*)d_in[17];
  const float* mixhws2_b= (const float*)d_in[18];
  const float* linHW    = (const float*)d_in[19];
  const float* linHb    = (const float*)d_in[20];
  const float* linWW    = (const float*)d_in[21];
  const float* linWb    = (const float*)d_in[22];
  const float* mixallW  = (const float*)d_in[23];
  const float* mixallb  = (const float*)d_in[24];
  const float* projW    = (const float*)d_in[25];
  const float* projb    = (const float*)d_in[26];
  const float* gatew    = (const float*)d_in[27];
  float* out = (float*)d_out;
  (void)in_sizes; (void)n_in; (void)out_size; (void)ws_size;

  const int M = 25088;  // 512*7*7
  char* ws = (char*)d_ws;
  size_t off = 0;
  auto carve = [&](size_t bytes) -> void* {
    void* p = ws + off;
    off += (bytes + 255) & ~(size_t)255;
    return p;
  };
  __bf16* xb     = (__bf16*)carve((size_t)M * 768 * 2);
  __bf16* Wcat   = (__bf16*)carve((size_t)2304 * 768 * 2);
  __bf16* Pb     = (__bf16*)carve((size_t)768 * 768 * 2);
  __bf16* Dt     = (__bf16*)carve((size_t)2304 * 768 * 2);
  __bf16* W2     = (__bf16*)carve((size_t)768 * 2304 * 2);
  float*  bcat   = (float*)carve(2304 * 4);
  float*  b2     = (float*)carve(768 * 4);
  __bf16* hws    = (__bf16*)carve((size_t)M * 2304 * 2);

  k_convert<<<9408, 256, 0, stream>>>(x, xb, (M * 768) / 8);
  k_prep<<<1164, 256, 0, stream>>>(Wh, Ww, Ws, projW, bh, bw, bs, mixallb, projb,
                                   Wcat, Pb, bcat, b2);
  k_transpose_cvt<<<dim3(72, 24), dim3(32, 8), 0, stream>>>(mixallW, Dt, 768, 2304);

  // fused: W2 = P.D (54 blocks) + [h|w|s] = gelu(x@[Wh|Ww|Ws]^T + bcat) (1764)
  k_gemm_fused<<<54 + 1764, 256, 0, stream>>>(Pb, Dt, W2, xb, Wcat, bcat, hws);
  // pool + gates + gate-apply, one block per batch
  k_poolgate<<<512, 256, 0, stream>>>(hws, convH_w, convH_b, convH2_k, convH2_b,
                                      mixhw_k, mixhw_b, mixhw2_k, mixhw2_b,
                                      mixhws_k, mixhws_b, mixhws2_k, mixhws2_b,
                                      linHW, linHb, linWW, linWb);
  // out = g0*(cat @ W2^T + b2) + g1*x  (M x 768, K=2304)
  k_gemm2<<<98 * 6, 256, 0, stream>>>(hws, W2, b2, out, x, gatew);
}

// Round 13
// 365.408 us; speedup vs baseline: 1.4540x; 1.0265x over previous
//
#include <hip/hip_runtime.h>
#include <cstdint>
#include <cstddef>

typedef __attribute__((ext_vector_type(8))) __bf16 bf16x8;
typedef __attribute__((ext_vector_type(4))) float f32x4;

__device__ __forceinline__ float sigm(float v) { return 1.0f / (1.0f + expf(-v)); }

__device__ __forceinline__ float gelu_fast(float v) {
  float u = v * (1.0f + 0.044715f * v * v);
  float z = 1.5957691216057308f * u;
  return v / (1.0f + __expf(-z));
}

__device__ __forceinline__ void async16(__bf16* lds, const __bf16* g) {
  __builtin_amdgcn_global_load_lds(
      (const __attribute__((address_space(1))) void*)g,
      (__attribute__((address_space(3))) void*)lds, 16, 0, 0);
}

// ---------------- merged prep: x convert + W converts + bcat + b2 + Dt ----------
// blocks [0,9408): x fp32->bf16; [9408,10572): W converts/bcat/b2; [10572,12300):
// mixallW transpose+convert (1728 = 72 x 24 tiles of 32x32).
__global__ __launch_bounds__(256) void k_prep_all(
    const float* __restrict__ x, __bf16* __restrict__ xb,
    const float* __restrict__ Wh, const float* __restrict__ Ww,
    const float* __restrict__ Ws, const float* __restrict__ projW,
    const float* __restrict__ bh, const float* __restrict__ bw,
    const float* __restrict__ bs, const float* __restrict__ mixallb,
    const float* __restrict__ projb, __bf16* __restrict__ Wcat,
    __bf16* __restrict__ Pb, float* __restrict__ bcat, float* __restrict__ b2,
    const float* __restrict__ mixallW, __bf16* __restrict__ Dt) {
  __shared__ float tsh[32][33];
  const int bid = blockIdx.x, t = threadIdx.x;
  if (bid < 9408) {
    const int i = bid * 256 + t;  // < 2408448
    const f32x4* s4 = (const f32x4*)x;
    f32x4 a = s4[2 * i], b = s4[2 * i + 1];
    bf16x8 o;
#pragma unroll
    for (int e = 0; e < 4; ++e) { o[e] = (__bf16)a[e]; o[4 + e] = (__bf16)b[e]; }
    ((bf16x8*)xb)[i] = o;
  } else if (bid < 10572) {
    const int pb_ = bid - 9408;
    if (pb_ < 1152) {
      const int seg = pb_ / 288, loc = pb_ % 288;
      const float* src = seg == 0 ? Wh : (seg == 1 ? Ww : (seg == 2 ? Ws : projW));
      __bf16* dst = seg == 3 ? Pb : Wcat + (size_t)seg * 589824;
      const int i = loc * 256 + t;
      const f32x4* s4 = (const f32x4*)src;
      f32x4 a = s4[2 * i], b = s4[2 * i + 1];
      bf16x8 o;
#pragma unroll
      for (int e = 0; e < 4; ++e) { o[e] = (__bf16)a[e]; o[4 + e] = (__bf16)b[e]; }
      ((bf16x8*)dst)[i] = o;
    } else if (pb_ < 1161) {
      const int i = (pb_ - 1152) * 256 + t;
      if (i < 2304)
        bcat[i] = i < 768 ? bh[i] : (i < 1536 ? bw[i - 768] : bs[i - 1536]);
    } else {
      const int d = (pb_ - 1161) * 256 + t;
      float acc = projb[d];
      const float* row = projW + (size_t)d * 768;
#pragma unroll 4
      for (int c = 0; c < 768; c += 4) {
        f32x4 p4 = *(const f32x4*)(row + c);
        f32x4 b4 = *(const f32x4*)(mixallb + c);
        acc += p4[0] * b4[0] + p4[1] * b4[1] + p4[2] * b4[2] + p4[3] * b4[3];
      }
      b2[d] = acc;
    }
  } else {
    // transpose mixallW (768 x 2304) -> Dt (2304 x 768)
    const int lb = bid - 10572;
    const int c0 = (lb % 72) * 32, r0 = (lb / 72) * 32;
    const int tx = t & 31, ty = t >> 5;  // 32 x 8
#pragma unroll
    for (int i = 0; i < 32; i += 8)
      tsh[ty + i][tx] = mixallW[(size_t)(r0 + ty + i) * 2304 + c0 + tx];
    __syncthreads();
#pragma unroll
    for (int i = 0; i < 32; i += 8)
      Dt[(size_t)(c0 + ty + i) * 768 + r0 + tx] = (__bf16)tsh[tx][ty + i];
  }
}

// ===== 256x128 GEMM body (BT layout), BK=32, 4 waves of 128x64, ring-3 LDS =====
// R8/R11-proven: 72KB ring-3, counted vmcnt(6), 2 blocks/CU, ~100 VGPR (no spill).
// Kstride = row stride of A/B; Klen = this block's K extent; koff = K offset.
// Swizzle (both-sides, rule #21): 16B chunk ch ^= (row>>1)&3 (R6-R11: conflicts=0).
// EPI 0: outB = gelu(acc+bias); EPI 2/5: outF = g0*(acc+bias)+g1*xres;
// EPI 3: outB = acc; EPI 6: outF[(rg-21760)*768+cg] = g0*acc (split-K partial).
template <int EPI>
__device__ __forceinline__ void gemm_body(
    __bf16* lds, const __bf16* __restrict__ A, const __bf16* __restrict__ B,
    const float* __restrict__ bias, __bf16* __restrict__ outB,
    float* __restrict__ outF, const float* __restrict__ xres,
    const float* __restrict__ gatew, int N, int Kstride, int Klen, int koff,
    int tm, int tn) {
  const int tid = threadIdx.x;
  const int lane = tid & 63, wid = tid >> 6;
  const int wr = wid >> 1, wc = wid & 1;

  const __bf16* Ag = A + (size_t)tm * 256 * Kstride + koff;
  const __bf16* Bg = B + (size_t)tn * 128 * Kstride + koff;

  auto stage = [&](int buf, int kt) {
    const int base = buf * 12288;
#pragma unroll
    for (int j = 0; j < 4; ++j) {
      const int lin = j * 256 + tid;
      const int row = lin >> 2, ch = lin & 3;
      async16(&lds[base + lin * 8],
              Ag + (size_t)row * Kstride + kt * 32 + ((ch ^ ((row >> 1) & 3)) << 3));
    }
#pragma unroll
    for (int j = 0; j < 2; ++j) {
      const int lin = j * 256 + tid;
      const int row = lin >> 2, ch = lin & 3;
      async16(&lds[base + 8192 + lin * 8],
              Bg + (size_t)row * Kstride + kt * 32 + ((ch ^ ((row >> 1) & 3)) << 3));
    }
  };

  f32x4 acc[8][4];
#pragma unroll
  for (int m = 0; m < 8; ++m)
#pragma unroll
    for (int n = 0; n < 4; ++n) acc[m][n] = f32x4{0.f, 0.f, 0.f, 0.f};

  const int kc = lane >> 4;
  const int rA = wr * 128 + (lane & 15);
  const int rB = wc * 64 + (lane & 15);
  const int chA = kc ^ ((rA >> 1) & 3);
  const int chB = kc ^ ((rB >> 1) & 3);
  const int NT = Klen >> 5;

  stage(0, 0);
  stage(1, 1);
  asm volatile("s_waitcnt vmcnt(6)" ::: "memory");
  __builtin_amdgcn_s_barrier();

  for (int t = 0; t < NT; ++t) {
    const int cb = (t % 3) * 12288;
    if (t + 2 < NT) stage((t + 2) % 3, t + 2);  // prefetch first
    bf16x8 af[8], bfv[4];
#pragma unroll
    for (int m = 0; m < 8; ++m)
      af[m] = *(const bf16x8*)&lds[cb + (rA + m * 16) * 32 + chA * 8];
#pragma unroll
    for (int n = 0; n < 4; ++n)
      bfv[n] = *(const bf16x8*)&lds[cb + 8192 + (rB + n * 16) * 32 + chB * 8];
    __builtin_amdgcn_s_setprio(1);
#pragma unroll
    for (int m = 0; m < 8; ++m)
#pragma unroll
      for (int n = 0; n < 4; ++n)
        acc[m][n] = __builtin_amdgcn_mfma_f32_16x16x32_bf16(af[m], bfv[n], acc[m][n], 0, 0, 0);
    __builtin_amdgcn_s_setprio(0);
    if (t + 2 < NT) { asm volatile("s_waitcnt vmcnt(6)" ::: "memory"); }
    else            { asm volatile("s_waitcnt vmcnt(0)" ::: "memory"); }
    __builtin_amdgcn_s_barrier();
  }

  // epilogue: C/D layout col=lane&15, row=(lane>>4)*4+reg  [m89]
  const int orow = (lane >> 4) * 4;
  const int ocol = lane & 15;
  float g0 = 0.f, g1 = 0.f;
  if constexpr (EPI == 2 || EPI == 5 || EPI == 6) { g0 = gatew[0]; g1 = gatew[1]; }
#pragma unroll
  for (int m = 0; m < 8; ++m) {
#pragma unroll
    for (int n = 0; n < 4; ++n) {
#pragma unroll
      for (int rr = 0; rr < 4; ++rr) {
        const int rg = tm * 256 + wr * 128 + m * 16 + orow + rr;
        const int cg = tn * 128 + wc * 64 + n * 16 + ocol;
        if constexpr (EPI == 0) {
          float v = acc[m][n][rr] + bias[cg];
          outB[(size_t)rg * N + cg] = (__bf16)gelu_fast(v);
        } else if constexpr (EPI == 2 || EPI == 5) {
          float v = acc[m][n][rr] + bias[cg];
          outF[(size_t)rg * N + cg] = g0 * v + g1 * xres[(size_t)rg * N + cg];
        } else if constexpr (EPI == 6) {
          outF[(size_t)(rg - 21760) * 768 + cg] = g0 * acc[m][n][rr];
        } else {
          outB[(size_t)rg * N + cg] = (__bf16)acc[m][n][rr];
        }
      }
    }
  }
}

__device__ __forceinline__ int swz_bij(int b, int nwg) {
  const int q = nwg >> 3, r = nwg & 7;
  const int xcd = b & 7, idx = b >> 3;
  return (xcd < r ? xcd * (q + 1) : r * (q + 1) + (xcd - r) * q) + idx;
}

// fused: W2 = P.D (blocks [0,54)) + GEMM1 (blocks [54, 54+1764))
__global__ __launch_bounds__(256, 2) void k_gemm_fused(
    const __bf16* __restrict__ Pb, const __bf16* __restrict__ Dt,
    __bf16* __restrict__ W2, const __bf16* __restrict__ xb,
    const __bf16* __restrict__ Wcat, const float* __restrict__ bcat,
    __bf16* __restrict__ hws) {
  __shared__ __bf16 lds[36864];  // 72 KiB, ring-3
  if (blockIdx.x < 54) {
    const int tm = blockIdx.x / 18, tn = blockIdx.x % 18;
    gemm_body<3>(lds, Pb, Dt, nullptr, W2, nullptr, nullptr, nullptr,
                 2304, 768, 768, 0, tm, tn);
  } else {
    const int wgid = swz_bij(blockIdx.x - 54, 1764);
    gemm_body<0>(lds, xb, Wcat, bcat, hws, nullptr, nullptr, nullptr,
                 2304, 768, 768, 0, wgid / 18, wgid % 18);
  }
}

// GEMM2 with tail split-K: M-tiles 0..84 full-K (510 blocks, XCD-swizzled);
// M-tiles 85..97 (rows 21760..25088) split K=2304 into 2x1152:
//   halfA (blocks [510,588)) writes affine part to out;
//   halfB (blocks [588,666)) writes g0*acc partial to pT; k_tailred adds.
__global__ __launch_bounds__(256, 2) void k_gemm2(
    const __bf16* __restrict__ hws, const __bf16* __restrict__ W2,
    const float* __restrict__ b2, float* __restrict__ out,
    const float* __restrict__ x, const float* __restrict__ gatew,
    float* __restrict__ pT) {
  __shared__ __bf16 lds[36864];
  const int bid = blockIdx.x;
  if (bid < 510) {
    const int wgid = swz_bij(bid, 510);
    gemm_body<2>(lds, hws, W2, b2, nullptr, out, x, gatew,
                 768, 2304, 2304, 0, wgid / 6, wgid % 6);
  } else if (bid < 588) {
    const int i = bid - 510;
    gemm_body<5>(lds, hws, W2, b2, nullptr, out, x, gatew,
                 768, 2304, 1152, 0, 85 + i / 6, i % 6);
  } else {
    const int i = bid - 588;
    gemm_body<6>(lds, hws, W2, b2, nullptr, pT, x, gatew,
                 768, 2304, 1152, 1152, 85 + i / 6, i % 6);
  }
}

// out[rows 21760..25088] += pT   (3328 x 768 fp32; 638976 f32x4 chunks)
__global__ __launch_bounds__(256) void k_tailred(float* __restrict__ out,
                                                 const float* __restrict__ pT) {
  const int i = blockIdx.x * 256 + threadIdx.x;
  if (i >= 638976) return;
  f32x4* o = (f32x4*)(out + (size_t)21760 * 768);
  f32x4 a = o[i];
  f32x4 b = ((const f32x4*)pT)[i];
#pragma unroll
  for (int e = 0; e < 4; ++e) a[e] += b[e];
  o[i] = a;
}

// ---------------- fused pool + gates + gate-apply (one block per batch) -------
__global__ __launch_bounds__(256) void k_poolgate(
    __bf16* __restrict__ hws, const float* __restrict__ convH_w,
    const float* __restrict__ convH_b, const float* __restrict__ convH2_k,
    const float* __restrict__ convH2_b, const float* __restrict__ mixhw_k,
    const float* __restrict__ mixhw_b, const float* __restrict__ mixhw2_k,
    const float* __restrict__ mixhw2_b, const float* __restrict__ mixhws_k,
    const float* __restrict__ mixhws_b, const float* __restrict__ mixhws2_k,
    const float* __restrict__ mixhws2_b, const float* __restrict__ linHW,
    const float* __restrict__ linHb, const float* __restrict__ linWW,
    const float* __restrict__ linWb) {
  const int b = blockIdx.x, t = threadIdx.x;
  const int lane = t & 63, wave = t >> 6;
  const size_t base = (size_t)b * 49 * 2304;

  __shared__ float red[4][14];
  __shared__ float s1v[768];
  __shared__ float hv[7], wv[7];
  __shared__ float ghl[7], ghwl[7];
  __shared__ float tc[770];
  __shared__ float gcl[768];

  // ---- phase 1: pool ----
  float hloc[7], wloc[7];
#pragma unroll
  for (int i = 0; i < 7; ++i) { hloc[i] = 0.f; wloc[i] = 0.f; }
  float sacc[8], sacc2[8];
#pragma unroll
  for (int e = 0; e < 8; ++e) { sacc[e] = 0.f; sacc2[e] = 0.f; }

  const bool isH = t < 96, isW = (t >= 96 && t < 192);
  const int off1 = isH ? t * 8 : (isW ? 768 + (t - 96) * 8 : 1536 + (t - 192) * 8);
  const int off2 = 1536 + (64 + t) * 8;

#pragma unroll
  for (int p = 0; p < 49; ++p) {
    const int hi = p / 7, wi = p % 7;
    const __bf16* row = hws + base + (size_t)p * 2304;
    bf16x8 v = *(const bf16x8*)(row + off1);
    float s8 = 0.f;
#pragma unroll
    for (int e = 0; e < 8; ++e) s8 += (float)v[e];
    if (isH) hloc[hi] += s8;
    else if (isW) wloc[wi] += s8;
    else {
#pragma unroll
      for (int e = 0; e < 8; ++e) sacc[e] += (float)v[e];
    }
    if (t < 32) {
      bf16x8 v2 = *(const bf16x8*)(row + off2);
#pragma unroll
      for (int e = 0; e < 8; ++e) sacc2[e] += (float)v2[e];
    }
  }

  if (t >= 192) {
#pragma unroll
    for (int e = 0; e < 8; ++e) s1v[(t - 192) * 8 + e] = sacc[e] * (1.f / 49.f);
  }
  if (t < 32) {
#pragma unroll
    for (int e = 0; e < 8; ++e) s1v[512 + t * 8 + e] = sacc2[e] * (1.f / 49.f);
  }

#pragma unroll
  for (int i = 0; i < 7; ++i) {
    float hvx = hloc[i], wvx = wloc[i];
#pragma unroll
    for (int s = 32; s; s >>= 1) { hvx += __shfl_xor(hvx, s); wvx += __shfl_xor(wvx, s); }
    if (lane == 0) { red[wave][i] = hvx; red[wave][7 + i] = wvx; }
  }
  if (t == 8) { tc[0] = 0.f; tc[769] = 0.f; }
  __syncthreads();

  if (t < 7) {
    hv[t] = (red[0][t] + red[1][t] + red[2][t] + red[3][t]) * (1.f / 5376.f);
  } else if (t >= 16 && t < 23) {
    const int i = t - 16;
    wv[i] = (red[0][7 + i] + red[1][7 + i] + red[2][7 + i] + red[3][7 + i]) * (1.f / 5376.f);
  }
  __syncthreads();

  // ---- phase 2: gates ----
  if (t < 7) {
    const float cw = convH_w[0], cbv = convH_b[0];
    const float k0 = convH2_k[0], k1 = convH2_k[1], k2 = convH2_k[2], b2v = convH2_b[0];
    const float um = t > 0 ? sigm(hv[t - 1] * cw + cbv) : 0.f;
    const float u0 = sigm(hv[t] * cw + cbv);
    const float up = t < 6 ? sigm(hv[t + 1] * cw + cbv) : 0.f;
    ghl[t] = sigm(k0 * um + k1 * u0 + k2 * up + b2v);

    const float a0 = mixhw_k[0], a1 = mixhw_k[1], ab = mixhw_b[0];
    const float q0 = mixhw2_k[0], q1 = mixhw2_k[1], q2 = mixhw2_k[2], qb = mixhw2_b[0];
    const float vm = t > 0 ? sigm(a0 * hv[t - 1] + a1 * wv[t - 1] + ab) : 0.f;
    const float v0 = sigm(a0 * hv[t] + a1 * wv[t] + ab);
    const float vp = t < 6 ? sigm(a0 * hv[t + 1] + a1 * wv[t + 1] + ab) : 0.f;
    ghwl[t] = sigm(q0 * vm + q1 * v0 + q2 * vp + qb);
  }

  const float m0 = mixhws_k[0], m1 = mixhws_k[1], m2 = mixhws_k[2], mb = mixhws_b[0];
#pragma unroll
  for (int j = 0; j < 3; ++j) {
    const int c = t + j * 256;
    float h2l = linHb[c], w2l = linWb[c];
#pragma unroll
    for (int i = 0; i < 7; ++i) {
      h2l += hv[i] * linHW[c * 7 + i];
      w2l += wv[i] * linWW[c * 7 + i];
    }
    tc[1 + c] = sigm(m0 * h2l + m1 * w2l + m2 * s1v[c] + mb);
  }
  __syncthreads();
  const float r0 = mixhws2_k[0], r1 = mixhws2_k[1], r2 = mixhws2_k[2], rb2 = mixhws2_b[0];
#pragma unroll
  for (int j = 0; j < 3; ++j) {
    const int c = t + j * 256;
    gcl[c] = sigm(r0 * tc[c] + r1 * tc[c + 1] + r2 * tc[c + 2] + rb2);
  }
  __syncthreads();

  // ---- phase 3: apply gates in place (re-read hits L2/L3) ----
  bf16x8* slab = (bf16x8*)(hws + base);
  for (int i = t; i < 49 * 288; i += 256) {
    const int k8 = i % 288, p = i / 288;
    bf16x8 v = slab[i];
    if (k8 < 96) {
      const float g = ghl[p / 7];
#pragma unroll
      for (int e = 0; e < 8; ++e) v[e] = (__bf16)((float)v[e] * g);
    } else if (k8 < 192) {
      const float g = ghwl[p % 7];
#pragma unroll
      for (int e = 0; e < 8; ++e) v[e] = (__bf16)((float)v[e] * g);
    } else {
      const float* gcp = gcl + (k8 - 192) * 8;
#pragma unroll
      for (int e = 0; e < 8; ++e) v[e] = (__bf16)((float)v[e] * gcp[e]);
    }
    slab[i] = v;
  }
}

// ---------------- launch ----------------
extern "C" void kernel_launch(void* const* d_in, const int* in_sizes, int n_in,
                              void* d_out, int out_size, void* d_ws, size_t ws_size,
                              hipStream_t stream) {
  const float* x        = (const float*)d_in[0];
  const float* Wh       = (const float*)d_in[1];
  const float* bh       = (const float*)d_in[2];
  const float* Ww       = (const float*)d_in[3];
  const float* bw       = (const float*)d_in[4];
  const float* Ws       = (const float*)d_in[5];
  const float* bs       = (const float*)d_in[6];
  const float* convH_w  = (const float*)d_in[7];
  const float* convH_b  = (const float*)d_in[8];
  const float* convH2_k = (const float*)d_in[9];
  const float* convH2_b = (const float*)d_in[10];
  const float* mixhw_k  = (const float*)d_in[11];
  const float* mixhw_b  = (const float*)d_in[12];
  const float* mixhw2_k = (const float*)d_in[13];
  const float* mixhw2_b = (const float*)d_in[14];
  const float* mixhws_k = (const float*)d_in[15];
  const float* mixhws_b = (const float*)d_in[16];
  const float* mixhws2_k= (const float*)d_in[17];
  const float* mixhws2_b= (const float*)d_in[18];
  const float* linHW    = (const float*)d_in[19];
  const float* linHb    = (const float*)d_in[20];
  const float* linWW    = (const float*)d_in[21];
  const float* linWb    = (const float*)d_in[22];
  const float* mixallW  = (const float*)d_in[23];
  const float* mixallb  = (const float*)d_in[24];
  const float* projW    = (const float*)d_in[25];
  const float* projb    = (const float*)d_in[26];
  const float* gatew    = (const float*)d_in[27];
  float* out = (float*)d_out;
  (void)in_sizes; (void)n_in; (void)out_size; (void)ws_size;

  const int M = 25088;  // 512*7*7
  char* ws = (char*)d_ws;
  size_t off = 0;
  auto carve = [&](size_t bytes) -> void* {
    void* p = ws + off;
    off += (bytes + 255) & ~(size_t)255;
    return p;
  };
  __bf16* xb     = (__bf16*)carve((size_t)M * 768 * 2);
  __bf16* Wcat   = (__bf16*)carve((size_t)2304 * 768 * 2);
  __bf16* Pb     = (__bf16*)carve((size_t)768 * 768 * 2);
  __bf16* Dt     = (__bf16*)carve((size_t)2304 * 768 * 2);
  __bf16* W2     = (__bf16*)carve((size_t)768 * 2304 * 2);
  float*  bcat   = (float*)carve(2304 * 4);
  float*  b2     = (float*)carve(768 * 4);
  __bf16* hws    = (__bf16*)carve((size_t)M * 2304 * 2);
  float*  pT     = (float*)carve((size_t)3328 * 768 * 4);

  // one merged prep dispatch: x convert + W converts + bcat + b2 + Dt transpose
  k_prep_all<<<12300, 256, 0, stream>>>(x, xb, Wh, Ww, Ws, projW, bh, bw, bs,
                                        mixallb, projb, Wcat, Pb, bcat, b2,
                                        mixallW, Dt);
  // fused: W2 = P.D (54 blocks) + [h|w|s] = gelu(x@[Wh|Ww|Ws]^T + bcat) (1764)
  k_gemm_fused<<<54 + 1764, 256, 0, stream>>>(Pb, Dt, W2, xb, Wcat, bcat, hws);
  // pool + gates + gate-apply, one block per batch
  k_poolgate<<<512, 256, 0, stream>>>(hws, convH_w, convH_b, convH2_k, convH2_b,
                                      mixhw_k, mixhw_b, mixhw2_k, mixhw2_b,
                                      mixhws_k, mixhws_b, mixhws2_k, mixhws2_b,
                                      linHW, linHb, linWW, linWb);
  // out = g0*(cat @ W2^T + b2) + g1*x  (M x 768, K=2304), tail split-K
  k_gemm2<<<666, 256, 0, stream>>>(hws, W2, b2, out, x, gatew, pT);
  k_tailred<<<2496, 256, 0, stream>>>(out, pT);
}